// Round 4
// baseline (9214.580 us; speedup 1.0000x reference)
//
#include <hip/hip_runtime.h>
#include <hip/hip_bf16.h>
#include <stdint.h>

// Seq2Seq LSTM: B=4096, H=512, E=128, 32 enc + 32 dec steps, V_tgt=128.
// Round 4: fused structure (validated equivalent to plain in R2==R3 bisect)
//          with FP32 OUTPUT (the R2/R3 failure was writing bf16 into a
//          float* d_out — reference returns float32).
//  - inputs fp32 (proven), output fp32; dtype flag probe kept as cheap safety
//  - input projection x@Wih^T + bih + bhh folded into per-vocab fp32 tables
//  - weights as canonical bf16 hi/lo pairs; GEMM runs 3 MFMA chains
//    (hh*Wh + hl*Wh + hh*Wl) => fp32-faithful (missing term ~2^-18 rel)
//  - h kept as bf16 hi+lo pair, c fp32
//  - gate-as-ntile B interleave => each lane owns i,f,g,o for its (row,hcol);
//    LSTM cell applied in the GEMM epilogue (no gates round-trip)
//  - decoder launch tt fuses outproj of h_{tt-1} as 32 extra blocks

#define NB     4096
#define SSRC   32
#define STGT   32
#define NVSRC  96
#define NVTGT  128
#define ED     128
#define HD     512
#define G4     2048   // 4*HD

typedef __attribute__((ext_vector_type(8))) short bf16x8;
typedef __attribute__((ext_vector_type(4))) float fx4;

__device__ __forceinline__ float sigf(float x) { return 1.0f / (1.0f + __expf(-x)); }
__device__ __forceinline__ float tanhfast(float x) { return 1.0f - 2.0f / (__expf(2.0f * x) + 1.0f); }

__device__ __forceinline__ float ldflag(const void* src, size_t i, int isf32) {
    return isf32 ? ((const float*)src)[i]
                 : __bfloat162float(((const __hip_bfloat16*)src)[i]);
}

// Probe: fp32 weights read as bf16 show |x|>8 / NaN shorts; true bf16 doesn't.
__global__ void detect_dtype(const void* probe, int* flag) {
    __shared__ int any;
    if (threadIdx.x == 0) any = 0;
    __syncthreads();
    const __hip_bfloat16* p = (const __hip_bfloat16*)probe;
    int bad = 0;
    for (int i = threadIdx.x; i < 4096; i += 256) {
        float v = __bfloat162float(p[i]);
        if (!(fabsf(v) <= 8.0f)) bad = 1;
    }
    if (bad) any = 1;
    __syncthreads();
    if (threadIdx.x == 0) *flag = any;
}

__global__ void convert_pair(const void* src, int n,
                             __hip_bfloat16* __restrict__ hi, __hip_bfloat16* __restrict__ lo,
                             const int* __restrict__ flag) {
    int i = blockIdx.x * 256 + threadIdx.x;
    if (i >= n) return;
    float f = ldflag(src, i, *flag);
    __hip_bfloat16 h = __float2bfloat16(f);
    hi[i] = h;
    lo[i] = __float2bfloat16(f - __bfloat162float(h));
}

// proj[v][g] = emb[v,:]·Wih[g,:] + bih[g] + bhh[g]  (fp32); also bout -> fp32
__global__ void build_tables(
    const void* emb_src, const void* eWih, const void* ebih, const void* ebhh,
    const void* emb_tgt, const void* dWih, const void* dbih, const void* dbhh,
    const void* bout,
    float* __restrict__ proj_src, float* __restrict__ proj_tgt,
    float* __restrict__ bout_f, const int* __restrict__ flagp)
{
    const int isf = *flagp;
    int idx = blockIdx.x * blockDim.x + threadIdx.x;
    if (blockIdx.x == 0 && threadIdx.x < NVTGT)
        bout_f[threadIdx.x] = ldflag(bout, threadIdx.x, isf);
    if (idx < NVSRC * G4) {
        int v = idx >> 11, g = idx & (G4 - 1);
        float s = ldflag(ebih, g, isf) + ldflag(ebhh, g, isf);
        for (int e = 0; e < ED; e++)
            s += ldflag(emb_src, (size_t)v * ED + e, isf) * ldflag(eWih, (size_t)g * ED + e, isf);
        proj_src[idx] = s;
    } else {
        int i2 = idx - NVSRC * G4;
        if (i2 < NVTGT * G4) {
            int v = i2 >> 11, g = i2 & (G4 - 1);
            float s = ldflag(dbih, g, isf) + ldflag(dbhh, g, isf);
            for (int e = 0; e < ED; e++)
                s += ldflag(emb_tgt, (size_t)v * ED + e, isf) * ldflag(dWih, (size_t)g * ED + e, isf);
            proj_tgt[i2] = s;
        }
    }
}

// One LSTM step. Blocks [0, n_gemm): 128 rows x 32 hcols (x4 gates) of the
// gates GEMM + fused cell epilogue. Blocks [n_gemm, ...): outproj of the
// PREVIOUS step's h (out_t) -> fp32 logits.
__global__ __launch_bounds__(256) void lstm_step(
    const __hip_bfloat16* __restrict__ hhi_r, const __hip_bfloat16* __restrict__ hlo_r,
    __hip_bfloat16* __restrict__ hhi_w, __hip_bfloat16* __restrict__ hlo_w,
    float* __restrict__ c_state,
    const float* __restrict__ proj,
    const int* __restrict__ seq, const int* __restrict__ lens,
    const __hip_bfloat16* __restrict__ Bhi, const __hip_bfloat16* __restrict__ Blo,
    int t, int is_enc, int n_gemm, int out_t,
    const __hip_bfloat16* __restrict__ WoutHi, const __hip_bfloat16* __restrict__ WoutLo,
    const float* __restrict__ bout_f,
    float* __restrict__ out)
{
    extern __shared__ unsigned short ls[];          // 4 x 128x64 bf16 = 64 KB
    unsigned short* lsAh = ls;
    unsigned short* lsAl = ls + 8192;
    unsigned short* lsBh = ls + 16384;
    unsigned short* lsBl = ls + 24576;

    const int tid = threadIdx.x;
    const int lane = tid & 63;
    const int wid  = tid >> 6;
    const int srow = lane >> 3;        // staging: row within 8-row group
    const int skc  = (lane & 7) << 3;  // staging: bf16 k-offset
    const int wm    = (wid >> 1) * 64; // wave m-offset
    const int wncol = wid & 1;         // wave n-column (0/1)
    const int quad  = lane >> 4;
    const int l15   = lane & 15;

    const bool is_gemm = (int)blockIdx.x < n_gemm;
    if (!is_gemm && out_t < 0) return;
    int m0, c0 = 0;
    int lr_[4];
    const __hip_bfloat16 *agh[4], *agl[4], *bgh[4], *bgl[4];

    if (is_gemm) {
        m0 = ((int)blockIdx.x >> 4) * 128;   // batch tile
        c0 = ((int)blockIdx.x & 15) * 32;    // hcol tile
        #pragma unroll
        for (int i = 0; i < 4; i++) {
            int lr = wid * 32 + i * 8 + srow;          // local row 0..127
            lr_[i] = lr;
            agh[i] = hhi_r + (size_t)(m0 + lr) * HD + skc;
            agl[i] = hlo_r + (size_t)(m0 + lr) * HD + skc;
            // local col lr -> (wavecol=lr>>6, gate=(lr>>4)&3, tcol=lr&15)
            int wr = ((lr >> 4) & 3) * HD + c0 + ((lr >> 6) << 4) + (lr & 15);
            bgh[i] = Bhi + (size_t)wr * HD + skc;
            bgl[i] = Blo + (size_t)wr * HD + skc;
        }
    } else {
        m0 = ((int)blockIdx.x - n_gemm) * 128;
        #pragma unroll
        for (int i = 0; i < 4; i++) {
            int lr = wid * 32 + i * 8 + srow;
            lr_[i] = lr;
            agh[i] = hhi_r + (size_t)(m0 + lr) * HD + skc;
            agl[i] = hlo_r + (size_t)(m0 + lr) * HD + skc;
            bgh[i] = WoutHi + (size_t)lr * HD + skc;   // Wout row = v
            bgl[i] = WoutLo + (size_t)lr * HD + skc;
        }
    }

    fx4 acc[4][4];
    #pragma unroll
    for (int i = 0; i < 4; i++)
        #pragma unroll
        for (int j = 0; j < 4; j++)
            acc[i][j] = fx4{0.f, 0.f, 0.f, 0.f};

    for (int k0 = 0; k0 < HD; k0 += 64) {
        uint4 vAh[4], vAl[4], vBh[4], vBl[4];
        #pragma unroll
        for (int i = 0; i < 4; i++) {
            vAh[i] = *(const uint4*)(agh[i] + k0);
            vAl[i] = *(const uint4*)(agl[i] + k0);
            vBh[i] = *(const uint4*)(bgh[i] + k0);
            vBl[i] = *(const uint4*)(bgl[i] + k0);
        }
        __syncthreads();
        #pragma unroll
        for (int i = 0; i < 4; i++) {
            int lb = lr_[i] * 64 + skc;
            *(uint4*)&lsAh[lb] = vAh[i];
            *(uint4*)&lsAl[lb] = vAl[i];
            *(uint4*)&lsBh[lb] = vBh[i];
            *(uint4*)&lsBl[lb] = vBl[i];
        }
        __syncthreads();
        #pragma unroll
        for (int kk = 0; kk < 64; kk += 32) {
            const int ko = kk + quad * 8;
            bf16x8 ah[4], al[4], bh[4], bl[4];
            #pragma unroll
            for (int mt = 0; mt < 4; mt++) {
                ah[mt] = *(const bf16x8*)&lsAh[(wm + mt * 16 + l15) * 64 + ko];
                al[mt] = *(const bf16x8*)&lsAl[(wm + mt * 16 + l15) * 64 + ko];
            }
            #pragma unroll
            for (int nt = 0; nt < 4; nt++) {
                bh[nt] = *(const bf16x8*)&lsBh[(wncol * 64 + nt * 16 + l15) * 64 + ko];
                bl[nt] = *(const bf16x8*)&lsBl[(wncol * 64 + nt * 16 + l15) * 64 + ko];
            }
            #pragma unroll
            for (int mt = 0; mt < 4; mt++)
                #pragma unroll
                for (int nt = 0; nt < 4; nt++) {
                    acc[mt][nt] = __builtin_amdgcn_mfma_f32_16x16x32_bf16(ah[mt], bh[nt], acc[mt][nt], 0, 0, 0);
                    acc[mt][nt] = __builtin_amdgcn_mfma_f32_16x16x32_bf16(al[mt], bh[nt], acc[mt][nt], 0, 0, 0);
                    acc[mt][nt] = __builtin_amdgcn_mfma_f32_16x16x32_bf16(ah[mt], bl[nt], acc[mt][nt], 0, 0, 0);
                }
        }
    }

    if (is_gemm) {
        // acc[mt][gate][r]: all 4 gates for (row, hcol) live in this lane
        const int hcol = c0 + wncol * 16 + l15;
        #pragma unroll
        for (int mt = 0; mt < 4; mt++) {
            #pragma unroll
            for (int r = 0; r < 4; r++) {
                int row = m0 + wm + mt * 16 + quad * 4 + r;   // batch index
                int tok = is_enc ? seq[row * SSRC + t]
                                 : (t == 0 ? 1 : seq[row * STGT + t - 1]);  // SOS=1
                const float* xp = proj + (size_t)tok * G4 + hcol;
                float gi = acc[mt][0][r] + xp[0];
                float gf = acc[mt][1][r] + xp[HD];
                float gg = acc[mt][2][r] + xp[2 * HD];
                float go = acc[mt][3][r] + xp[3 * HD];
                float ii = sigf(gi), ff = sigf(gf), oo = sigf(go);
                float g2 = tanhfast(gg);
                size_t off = (size_t)row * HD + hcol;
                float cold = c_state[off];
                float c2 = ff * cold + ii * g2;
                float h2 = oo * tanhfast(c2);
                if (is_enc && t >= lens[row]) {   // pack_padded semantics
                    c2 = cold;
                    h2 = __bfloat162float(hhi_r[off]) + __bfloat162float(hlo_r[off]);
                }
                c_state[off] = c2;
                __hip_bfloat16 hh = __float2bfloat16(h2);
                hhi_w[off] = hh;
                hlo_w[off] = __float2bfloat16(h2 - __bfloat162float(hh));
            }
        }
    } else {
        // logits[:, out_t, :] = h_prev @ Wout^T + bout  (FP32 output)
        #pragma unroll
        for (int mt = 0; mt < 4; mt++) {
            #pragma unroll
            for (int nt = 0; nt < 4; nt++) {
                int v = wncol * 64 + nt * 16 + l15;
                float bo = bout_f[v];
                #pragma unroll
                for (int r = 0; r < 4; r++) {
                    int row = m0 + wm + mt * 16 + quad * 4 + r;
                    out[((size_t)row * STGT + out_t) * NVTGT + v] = acc[mt][nt][r] + bo;
                }
            }
        }
    }
}

extern "C" void kernel_launch(void* const* d_in, const int* in_sizes, int n_in,
                              void* d_out, int out_size, void* d_ws, size_t ws_size,
                              hipStream_t stream) {
    (void)in_sizes; (void)n_in; (void)out_size; (void)ws_size;
    const int* src_seq = (const int*)d_in[0];
    const int* src_len = (const int*)d_in[1];
    const int* tgt_seq = (const int*)d_in[2];
    const void* emb_src = d_in[3];
    const void* eWih = d_in[4];
    const void* eWhh = d_in[5];
    const void* ebih = d_in[6];
    const void* ebhh = d_in[7];
    const void* emb_tgt = d_in[8];
    const void* dWih = d_in[9];
    const void* dWhh = d_in[10];
    const void* dbih = d_in[11];
    const void* dbhh = d_in[12];
    const void* Wout = d_in[13];
    const void* bout = d_in[14];
    float* out = (float*)d_out;   // reference output dtype is float32

    char* ws = (char*)d_ws;
    size_t off = 0;
    auto carve = [&](size_t bytes) { void* p = ws + off; off += (bytes + 255) & ~(size_t)255; return p; };
    int*   flag     = (int*)carve(256);
    float* proj_src = (float*)carve((size_t)NVSRC * G4 * 4);
    float* proj_tgt = (float*)carve((size_t)NVTGT * G4 * 4);
    float* bout_f   = (float*)carve(NVTGT * 4);
    float* c_state  = (float*)carve((size_t)NB * HD * 4);
    __hip_bfloat16* h_hi[2];
    __hip_bfloat16* h_lo[2];
    for (int i = 0; i < 2; i++) {
        h_hi[i] = (__hip_bfloat16*)carve((size_t)NB * HD * 2);
        h_lo[i] = (__hip_bfloat16*)carve((size_t)NB * HD * 2);
    }
    __hip_bfloat16* eW_hi = (__hip_bfloat16*)carve((size_t)G4 * HD * 2);
    __hip_bfloat16* eW_lo = (__hip_bfloat16*)carve((size_t)G4 * HD * 2);
    __hip_bfloat16* dW_hi = (__hip_bfloat16*)carve((size_t)G4 * HD * 2);
    __hip_bfloat16* dW_lo = (__hip_bfloat16*)carve((size_t)G4 * HD * 2);
    __hip_bfloat16* Wo_hi = (__hip_bfloat16*)carve((size_t)NVTGT * HD * 2);
    __hip_bfloat16* Wo_lo = (__hip_bfloat16*)carve((size_t)NVTGT * HD * 2);

    hipMemsetAsync(c_state, 0, (size_t)NB * HD * 4, stream);
    hipMemsetAsync(h_hi[0], 0, (size_t)NB * HD * 2, stream);
    hipMemsetAsync(h_lo[0], 0, (size_t)NB * HD * 2, stream);

    detect_dtype<<<dim3(1), dim3(256), 0, stream>>>(eWhh, flag);
    convert_pair<<<dim3(G4 * HD / 256), dim3(256), 0, stream>>>(eWhh, G4 * HD, eW_hi, eW_lo, flag);
    convert_pair<<<dim3(G4 * HD / 256), dim3(256), 0, stream>>>(dWhh, G4 * HD, dW_hi, dW_lo, flag);
    convert_pair<<<dim3(NVTGT * HD / 256), dim3(256), 0, stream>>>(Wout, NVTGT * HD, Wo_hi, Wo_lo, flag);
    build_tables<<<dim3((NVSRC + NVTGT) * G4 / 256), dim3(256), 0, stream>>>(
        emb_src, eWih, ebih, ebhh, emb_tgt, dWih, dbih, dbhh, bout,
        proj_src, proj_tgt, bout_f, flag);

    const size_t lds = 4 * 128 * 64 * sizeof(unsigned short);  // 64 KB
    // encoder: steps s=0..31, masked update
    for (int s = 0; s < 32; s++) {
        lstm_step<<<dim3(512), dim3(256), lds, stream>>>(
            h_hi[s & 1], h_lo[s & 1], h_hi[(s + 1) & 1], h_lo[(s + 1) & 1], c_state,
            proj_src, src_seq, src_len, eW_hi, eW_lo, s, 1, 512, -1,
            Wo_hi, Wo_lo, bout_f, out);
    }
    // decoder: steps tt=0..31; 32 extra blocks project h_{tt-1} -> out[:,tt-1,:]
    for (int tt = 0; tt < 32; tt++) {
        int s = 32 + tt;
        lstm_step<<<dim3(544), dim3(256), lds, stream>>>(
            h_hi[s & 1], h_lo[s & 1], h_hi[(s + 1) & 1], h_lo[(s + 1) & 1], c_state,
            proj_tgt, tgt_seq, nullptr, dW_hi, dW_lo, tt, 0, 512, tt - 1,
            Wo_hi, Wo_lo, bout_f, out);
    }
    // tail: outproj of h after decoder step 31 (parity 0)
    lstm_step<<<dim3(32), dim3(256), lds, stream>>>(
        h_hi[0], h_lo[0], h_hi[1], h_lo[1], c_state,
        proj_tgt, tgt_seq, nullptr, dW_hi, dW_lo, 0, 0, 0, 31,
        Wo_hi, Wo_lo, bout_f, out);
}

// Round 5
// 3060.662 us; speedup vs baseline: 3.0106x; 3.0106x over previous
//
#include <hip/hip_runtime.h>
#include <hip/hip_bf16.h>
#include <stdint.h>

// Seq2Seq LSTM: B=4096, H=512, E=128, 32 enc + 32 dec steps, V_tgt=128.
// Round 5: kill the R4 scratch spill (283 MB/dispatch writeback, VGPR=108
// with dynamic LDS hiding the real occupancy limit from the allocator).
//  - global_load_lds width-16 staging (no staging VGPRs -> no spill)
//  - static 64KB __shared__ + __launch_bounds__(256,2)
//  - XOR bank swizzle on k-chunks (R4: 6.7M LDS bank conflicts)
//  - gates GEMM: 3 MFMA chains (fp32-faithful); outproj blocks: 1 chain
//  - fused cell epilogue, fp32 logits output (proven R4)

#define NB     4096
#define SSRC   32
#define STGT   32
#define NVSRC  96
#define NVTGT  128
#define ED     128
#define HD     512
#define G4     2048   // 4*HD

typedef __attribute__((ext_vector_type(8))) short bf16x8;
typedef __attribute__((ext_vector_type(4))) float fx4;

#define AS_G __attribute__((address_space(1)))
#define AS_L __attribute__((address_space(3)))

__device__ __forceinline__ void gl2lds16(const void* g, void* l) {
    // async global->LDS DMA, 16B/lane; LDS dest = wave-uniform base + lane*16
    __builtin_amdgcn_global_load_lds((const AS_G uint32_t*)g, (AS_L uint32_t*)l, 16, 0, 0);
}

__device__ __forceinline__ float sigf(float x) { return 1.0f / (1.0f + __expf(-x)); }
__device__ __forceinline__ float tanhfast(float x) { return 1.0f - 2.0f / (__expf(2.0f * x) + 1.0f); }

__device__ __forceinline__ float ldflag(const void* src, size_t i, int isf32) {
    return isf32 ? ((const float*)src)[i]
                 : __bfloat162float(((const __hip_bfloat16*)src)[i]);
}

__global__ void detect_dtype(const void* probe, int* flag) {
    __shared__ int any;
    if (threadIdx.x == 0) any = 0;
    __syncthreads();
    const __hip_bfloat16* p = (const __hip_bfloat16*)probe;
    int bad = 0;
    for (int i = threadIdx.x; i < 4096; i += 256) {
        float v = __bfloat162float(p[i]);
        if (!(fabsf(v) <= 8.0f)) bad = 1;
    }
    if (bad) any = 1;
    __syncthreads();
    if (threadIdx.x == 0) *flag = any;
}

__global__ void convert_pair(const void* src, int n,
                             __hip_bfloat16* __restrict__ hi, __hip_bfloat16* __restrict__ lo,
                             const int* __restrict__ flag) {
    int i = blockIdx.x * 256 + threadIdx.x;
    if (i >= n) return;
    float f = ldflag(src, i, *flag);
    __hip_bfloat16 h = __float2bfloat16(f);
    hi[i] = h;
    lo[i] = __float2bfloat16(f - __bfloat162float(h));
}

// proj[v][g] = emb[v,:]·Wih[g,:] + bih[g] + bhh[g]  (fp32); also bout -> fp32
__global__ void build_tables(
    const void* emb_src, const void* eWih, const void* ebih, const void* ebhh,
    const void* emb_tgt, const void* dWih, const void* dbih, const void* dbhh,
    const void* bout,
    float* __restrict__ proj_src, float* __restrict__ proj_tgt,
    float* __restrict__ bout_f, const int* __restrict__ flagp)
{
    const int isf = *flagp;
    int idx = blockIdx.x * blockDim.x + threadIdx.x;
    if (blockIdx.x == 0 && threadIdx.x < NVTGT)
        bout_f[threadIdx.x] = ldflag(bout, threadIdx.x, isf);
    if (idx < NVSRC * G4) {
        int v = idx >> 11, g = idx & (G4 - 1);
        float s = ldflag(ebih, g, isf) + ldflag(ebhh, g, isf);
        for (int e = 0; e < ED; e++)
            s += ldflag(emb_src, (size_t)v * ED + e, isf) * ldflag(eWih, (size_t)g * ED + e, isf);
        proj_src[idx] = s;
    } else {
        int i2 = idx - NVSRC * G4;
        if (i2 < NVTGT * G4) {
            int v = i2 >> 11, g = i2 & (G4 - 1);
            float s = ldflag(dbih, g, isf) + ldflag(dbhh, g, isf);
            for (int e = 0; e < ED; e++)
                s += ldflag(emb_tgt, (size_t)v * ED + e, isf) * ldflag(dWih, (size_t)g * ED + e, isf);
            proj_tgt[i2] = s;
        }
    }
}

// One LSTM step. Blocks [0,n_gemm): 128 rows x 32 hcols (x4 gates) of the
// gates GEMM + fused cell epilogue (3 MFMA chains). Blocks [n_gemm,...):
// outproj of the PREVIOUS step's h -> fp32 logits (1 chain).
__global__ __launch_bounds__(256, 2) void lstm_step(
    const __hip_bfloat16* __restrict__ hhi_r, const __hip_bfloat16* __restrict__ hlo_r,
    __hip_bfloat16* __restrict__ hhi_w, __hip_bfloat16* __restrict__ hlo_w,
    float* __restrict__ c_state,
    const float* __restrict__ proj,
    const int* __restrict__ seq, const int* __restrict__ lens,
    const __hip_bfloat16* __restrict__ Bhi, const __hip_bfloat16* __restrict__ Blo,
    int t, int is_enc, int n_gemm, int out_t,
    const __hip_bfloat16* __restrict__ WoutHi, const __hip_bfloat16* __restrict__ WoutLo,
    const float* __restrict__ bout_f,
    float* __restrict__ out)
{
    __shared__ __align__(16) unsigned short lsAh[128 * 64];
    __shared__ __align__(16) unsigned short lsAl[128 * 64];
    __shared__ __align__(16) unsigned short lsBh[128 * 64];
    __shared__ __align__(16) unsigned short lsBl[128 * 64];

    const int tid = threadIdx.x;
    const int lane = tid & 63;
    const int wid  = tid >> 6;
    const int srow = lane >> 3;                    // staging row-in-group (=row&7)
    const int skc  = (((lane & 7) ^ srow)) << 3;   // XOR-swizzled k-chunk offset
    const int wm    = (wid >> 1) * 64;             // wave m-offset
    const int wncol = wid & 1;                     // wave n-column (0/1)
    const int quad  = lane >> 4;
    const int l15   = lane & 15;
    const int bsw   = (l15 & 7);                   // fragment row&7 (bank swizzle)

    const bool is_gemm = (int)blockIdx.x < n_gemm;
    if (!is_gemm && out_t < 0) return;
    int m0, c0 = 0;
    const __hip_bfloat16 *agh[4], *agl[4], *bgh[4], *bgl[4];

    if (is_gemm) {
        m0 = ((int)blockIdx.x >> 4) * 128;   // batch tile
        c0 = ((int)blockIdx.x & 15) * 32;    // hcol tile
        #pragma unroll
        for (int i = 0; i < 4; i++) {
            int lr = wid * 32 + i * 8 + srow;          // local row 0..127
            agh[i] = hhi_r + (size_t)(m0 + lr) * HD + skc;
            agl[i] = hlo_r + (size_t)(m0 + lr) * HD + skc;
            // local col lr -> (wavecol=lr>>6, gate=(lr>>4)&3, tcol=lr&15)
            int wr = ((lr >> 4) & 3) * HD + c0 + ((lr >> 6) << 4) + (lr & 15);
            bgh[i] = Bhi + (size_t)wr * HD + skc;
            bgl[i] = Blo + (size_t)wr * HD + skc;
        }
    } else {
        m0 = ((int)blockIdx.x - n_gemm) * 128;
        #pragma unroll
        for (int i = 0; i < 4; i++) {
            int lr = wid * 32 + i * 8 + srow;
            agh[i] = hhi_r + (size_t)(m0 + lr) * HD + skc;
            agl[i] = hlo_r + (size_t)(m0 + lr) * HD + skc;   // unused (1-chain)
            bgh[i] = WoutHi + (size_t)lr * HD + skc;         // Wout row = v
            bgl[i] = WoutLo + (size_t)lr * HD + skc;         // unused
        }
    }

    fx4 acc[4][4];
    #pragma unroll
    for (int i = 0; i < 4; i++)
        #pragma unroll
        for (int j = 0; j < 4; j++)
            acc[i][j] = fx4{0.f, 0.f, 0.f, 0.f};

    for (int k0 = 0; k0 < HD; k0 += 64) {
        __syncthreads();   // protect LDS while still being read
        #pragma unroll
        for (int i = 0; i < 4; i++) {
            int lb = (wid * 32 + i * 8) * 64;          // wave-uniform LDS base
            gl2lds16(agh[i] + k0, &lsAh[lb]);
            gl2lds16(bgh[i] + k0, &lsBh[lb]);
            if (is_gemm) {
                gl2lds16(agl[i] + k0, &lsAl[lb]);
                gl2lds16(bgl[i] + k0, &lsBl[lb]);
            }
        }
        __syncthreads();   // drains vmcnt before barrier
        #pragma unroll
        for (int kk = 0; kk < 64; kk += 32) {
            const int kc = (kk >> 3) + quad;           // global k-chunk 0..7
            const int sw = ((kc ^ bsw) << 3);          // swizzled column (shorts)
            bf16x8 ah[4], bh[4];
            #pragma unroll
            for (int mt = 0; mt < 4; mt++)
                ah[mt] = *(const bf16x8*)&lsAh[(wm + mt * 16 + l15) * 64 + sw];
            #pragma unroll
            for (int nt = 0; nt < 4; nt++)
                bh[nt] = *(const bf16x8*)&lsBh[(wncol * 64 + nt * 16 + l15) * 64 + sw];
            if (is_gemm) {
                bf16x8 al[4], bl[4];
                #pragma unroll
                for (int mt = 0; mt < 4; mt++)
                    al[mt] = *(const bf16x8*)&lsAl[(wm + mt * 16 + l15) * 64 + sw];
                #pragma unroll
                for (int nt = 0; nt < 4; nt++)
                    bl[nt] = *(const bf16x8*)&lsBl[(wncol * 64 + nt * 16 + l15) * 64 + sw];
                #pragma unroll
                for (int mt = 0; mt < 4; mt++)
                    #pragma unroll
                    for (int nt = 0; nt < 4; nt++) {
                        acc[mt][nt] = __builtin_amdgcn_mfma_f32_16x16x32_bf16(ah[mt], bh[nt], acc[mt][nt], 0, 0, 0);
                        acc[mt][nt] = __builtin_amdgcn_mfma_f32_16x16x32_bf16(al[mt], bh[nt], acc[mt][nt], 0, 0, 0);
                        acc[mt][nt] = __builtin_amdgcn_mfma_f32_16x16x32_bf16(ah[mt], bl[nt], acc[mt][nt], 0, 0, 0);
                    }
            } else {
                #pragma unroll
                for (int mt = 0; mt < 4; mt++)
                    #pragma unroll
                    for (int nt = 0; nt < 4; nt++)
                        acc[mt][nt] = __builtin_amdgcn_mfma_f32_16x16x32_bf16(ah[mt], bh[nt], acc[mt][nt], 0, 0, 0);
            }
        }
    }

    if (is_gemm) {
        // acc[mt][gate][r]: all 4 gates for (row, hcol) live in this lane
        const int hcol = c0 + wncol * 16 + l15;
        #pragma unroll
        for (int mt = 0; mt < 4; mt++) {
            #pragma unroll
            for (int r = 0; r < 4; r++) {
                int row = m0 + wm + mt * 16 + quad * 4 + r;   // batch index
                int tok = is_enc ? seq[row * SSRC + t]
                                 : (t == 0 ? 1 : seq[row * STGT + t - 1]);  // SOS=1
                const float* xp = proj + (size_t)tok * G4 + hcol;
                float gi = acc[mt][0][r] + xp[0];
                float gf = acc[mt][1][r] + xp[HD];
                float gg = acc[mt][2][r] + xp[2 * HD];
                float go = acc[mt][3][r] + xp[3 * HD];
                float ii = sigf(gi), ff = sigf(gf), oo = sigf(go);
                float g2 = tanhfast(gg);
                size_t off = (size_t)row * HD + hcol;
                float cold = c_state[off];
                float c2 = ff * cold + ii * g2;
                float h2 = oo * tanhfast(c2);
                if (is_enc && t >= lens[row]) {   // pack_padded semantics
                    c2 = cold;
                    h2 = __bfloat162float(hhi_r[off]) + __bfloat162float(hlo_r[off]);
                }
                c_state[off] = c2;
                __hip_bfloat16 hh = __float2bfloat16(h2);
                hhi_w[off] = hh;
                hlo_w[off] = __float2bfloat16(h2 - __bfloat162float(hh));
            }
        }
    } else {
        // logits[:, out_t, :] = h_prev @ Wout^T + bout  (fp32 output)
        #pragma unroll
        for (int mt = 0; mt < 4; mt++) {
            #pragma unroll
            for (int nt = 0; nt < 4; nt++) {
                int v = wncol * 64 + nt * 16 + l15;
                float bo = bout_f[v];
                #pragma unroll
                for (int r = 0; r < 4; r++) {
                    int row = m0 + wm + mt * 16 + quad * 4 + r;
                    out[((size_t)row * STGT + out_t) * NVTGT + v] = acc[mt][nt][r] + bo;
                }
            }
        }
    }
}

extern "C" void kernel_launch(void* const* d_in, const int* in_sizes, int n_in,
                              void* d_out, int out_size, void* d_ws, size_t ws_size,
                              hipStream_t stream) {
    (void)in_sizes; (void)n_in; (void)out_size; (void)ws_size;
    const int* src_seq = (const int*)d_in[0];
    const int* src_len = (const int*)d_in[1];
    const int* tgt_seq = (const int*)d_in[2];
    const void* emb_src = d_in[3];
    const void* eWih = d_in[4];
    const void* eWhh = d_in[5];
    const void* ebih = d_in[6];
    const void* ebhh = d_in[7];
    const void* emb_tgt = d_in[8];
    const void* dWih = d_in[9];
    const void* dWhh = d_in[10];
    const void* dbih = d_in[11];
    const void* dbhh = d_in[12];
    const void* Wout = d_in[13];
    const void* bout = d_in[14];
    float* out = (float*)d_out;   // reference output dtype is float32

    char* ws = (char*)d_ws;
    size_t off = 0;
    auto carve = [&](size_t bytes) { void* p = ws + off; off += (bytes + 255) & ~(size_t)255; return p; };
    int*   flag     = (int*)carve(256);
    float* proj_src = (float*)carve((size_t)NVSRC * G4 * 4);
    float* proj_tgt = (float*)carve((size_t)NVTGT * G4 * 4);
    float* bout_f   = (float*)carve(NVTGT * 4);
    float* c_state  = (float*)carve((size_t)NB * HD * 4);
    __hip_bfloat16* h_hi[2];
    __hip_bfloat16* h_lo[2];
    for (int i = 0; i < 2; i++) {
        h_hi[i] = (__hip_bfloat16*)carve((size_t)NB * HD * 2);
        h_lo[i] = (__hip_bfloat16*)carve((size_t)NB * HD * 2);
    }
    __hip_bfloat16* eW_hi = (__hip_bfloat16*)carve((size_t)G4 * HD * 2);
    __hip_bfloat16* eW_lo = (__hip_bfloat16*)carve((size_t)G4 * HD * 2);
    __hip_bfloat16* dW_hi = (__hip_bfloat16*)carve((size_t)G4 * HD * 2);
    __hip_bfloat16* dW_lo = (__hip_bfloat16*)carve((size_t)G4 * HD * 2);
    __hip_bfloat16* Wo_hi = (__hip_bfloat16*)carve((size_t)NVTGT * HD * 2);
    __hip_bfloat16* Wo_lo = (__hip_bfloat16*)carve((size_t)NVTGT * HD * 2);

    hipMemsetAsync(c_state, 0, (size_t)NB * HD * 4, stream);
    hipMemsetAsync(h_hi[0], 0, (size_t)NB * HD * 2, stream);
    hipMemsetAsync(h_lo[0], 0, (size_t)NB * HD * 2, stream);

    detect_dtype<<<dim3(1), dim3(256), 0, stream>>>(eWhh, flag);
    convert_pair<<<dim3(G4 * HD / 256), dim3(256), 0, stream>>>(eWhh, G4 * HD, eW_hi, eW_lo, flag);
    convert_pair<<<dim3(G4 * HD / 256), dim3(256), 0, stream>>>(dWhh, G4 * HD, dW_hi, dW_lo, flag);
    convert_pair<<<dim3(NVTGT * HD / 256), dim3(256), 0, stream>>>(Wout, NVTGT * HD, Wo_hi, Wo_lo, flag);
    build_tables<<<dim3((NVSRC + NVTGT) * G4 / 256), dim3(256), 0, stream>>>(
        emb_src, eWih, ebih, ebhh, emb_tgt, dWih, dbih, dbhh, bout,
        proj_src, proj_tgt, bout_f, flag);

    // encoder: steps s=0..31, masked update
    for (int s = 0; s < 32; s++) {
        lstm_step<<<dim3(512), dim3(256), 0, stream>>>(
            h_hi[s & 1], h_lo[s & 1], h_hi[(s + 1) & 1], h_lo[(s + 1) & 1], c_state,
            proj_src, src_seq, src_len, eW_hi, eW_lo, s, 1, 512, -1,
            Wo_hi, Wo_lo, bout_f, out);
    }
    // decoder: steps tt=0..31; 32 extra blocks project h_{tt-1} -> out[:,tt-1,:]
    for (int tt = 0; tt < 32; tt++) {
        int s = 32 + tt;
        lstm_step<<<dim3(544), dim3(256), 0, stream>>>(
            h_hi[s & 1], h_lo[s & 1], h_hi[(s + 1) & 1], h_lo[(s + 1) & 1], c_state,
            proj_tgt, tgt_seq, nullptr, dW_hi, dW_lo, tt, 0, 512, tt - 1,
            Wo_hi, Wo_lo, bout_f, out);
    }
    // tail: outproj of h after decoder step 31 (parity 0)
    lstm_step<<<dim3(32), dim3(256), 0, stream>>>(
        h_hi[0], h_lo[0], h_hi[1], h_lo[1], c_state,
        proj_tgt, tgt_seq, nullptr, dW_hi, dW_lo, 0, 0, 0, 31,
        Wo_hi, Wo_lo, bout_f, out);
}

// Round 6
// 1979.839 us; speedup vs baseline: 4.6542x; 1.5459x over previous
//
#include <hip/hip_runtime.h>
#include <hip/hip_bf16.h>
#include <hip/hip_fp16.h>
#include <stdint.h>

// Seq2Seq LSTM: B=4096, H=512, E=128, 32 enc + 32 dec steps, V_tgt=128.
// Round 6: single-chain FP16 recurrence + XCD-swizzled tiles + fast tables.
//  - h recomputed from fp32 c each step => h/W quantization is fresh noise,
//    not compounding: fp16 (10-bit mantissa) single chain suffices
//    (bf16 1-chain tail measured +2.4e-4 in R5; fp16 is 8x finer)
//  - staging halves (no hi/lo pairs): 128 MB/step; XCD swizzle makes the
//    per-XCD working set 2.5 MB < 4 MB L2
//  - build_tables: wave-per-(8v x 64g), coalesced float2 + butterfly reduce
//    (R5: 157 us latency-bound on uncoalesced Wih rows)
//  - fused cell epilogue, fp32 logits out (proven R4/R5)

#define NB     4096
#define SSRC   32
#define STGT   32
#define NVSRC  96
#define NVTGT  128
#define ED     128
#define HD     512
#define G4     2048   // 4*HD

typedef __attribute__((ext_vector_type(8))) _Float16 half8;
typedef __attribute__((ext_vector_type(4))) float fx4;

#define AS_G __attribute__((address_space(1)))
#define AS_L __attribute__((address_space(3)))

__device__ __forceinline__ void gl2lds16(const void* g, void* l) {
    // async global->LDS DMA, 16B/lane; LDS dest = wave-uniform base + lane*16
    __builtin_amdgcn_global_load_lds((const AS_G uint32_t*)g, (AS_L uint32_t*)l, 16, 0, 0);
}

__device__ __forceinline__ float sigf(float x) { return 1.0f / (1.0f + __expf(-x)); }
__device__ __forceinline__ float tanhfast(float x) { return 1.0f - 2.0f / (__expf(2.0f * x) + 1.0f); }

__global__ void convert_half(const float* __restrict__ src, int n, _Float16* __restrict__ dst) {
    int i = blockIdx.x * 256 + threadIdx.x;
    if (i < n) dst[i] = (_Float16)src[i];
}

__global__ void prep_bout(const float* __restrict__ bout, float* __restrict__ bout_f) {
    if (threadIdx.x < NVTGT) bout_f[threadIdx.x] = bout[threadIdx.x];
}

// proj[v][g] = emb[v,:]·Wih[g,:] + bih[g] + bhh[g]  (fp32, exact-ish)
// wave w handles 8 v x 64 g; lane owns e-slice {2*lane, 2*lane+1};
// butterfly-reduce per g, lane g64 retains. All reads coalesced.
__global__ __launch_bounds__(256) void build_tables(
    const float* __restrict__ emb, const float* __restrict__ Wih,
    const float* __restrict__ bih, const float* __restrict__ bhh,
    float* __restrict__ proj)
{
    const int lane = threadIdx.x & 63;
    const int w = blockIdx.x * 4 + (threadIdx.x >> 6);
    const int v0 = (w >> 5) * 8;
    const int g0 = (w & 31) * 64;

    float2 ev[8];
    #pragma unroll
    for (int i = 0; i < 8; i++)
        ev[i] = *(const float2*)&emb[(size_t)(v0 + i) * ED + 2 * lane];

    float r[8];
    for (int g64 = 0; g64 < 64; g64++) {
        float2 wv = *(const float2*)&Wih[(size_t)(g0 + g64) * ED + 2 * lane];
        float p[8];
        #pragma unroll
        for (int i = 0; i < 8; i++) p[i] = ev[i].x * wv.x + ev[i].y * wv.y;
        #pragma unroll
        for (int off = 1; off < 64; off <<= 1)
            #pragma unroll
            for (int i = 0; i < 8; i++) p[i] += __shfl_xor(p[i], off);
        if (lane == g64)
            #pragma unroll
            for (int i = 0; i < 8; i++) r[i] = p[i];
    }
    float bb = bih[g0 + lane] + bhh[g0 + lane];
    #pragma unroll
    for (int i = 0; i < 8; i++)
        proj[(size_t)(v0 + i) * G4 + g0 + lane] = r[i] + bb;
}

// One LSTM step. Blocks [0,n_gemm): 128 rows x 32 hcols (x4 gates) of the
// gates GEMM + fused cell epilogue. Blocks [n_gemm,...): outproj of the
// PREVIOUS step's h -> fp32 logits. Single fp16 MFMA chain everywhere.
__global__ __launch_bounds__(256, 2) void lstm_step(
    const _Float16* __restrict__ h_r, _Float16* __restrict__ h_w,
    float* __restrict__ c_state,
    const float* __restrict__ proj,
    const int* __restrict__ seq, const int* __restrict__ lens,
    const _Float16* __restrict__ W,
    int t, int is_enc, int n_gemm, int out_t,
    const _Float16* __restrict__ Wout, const float* __restrict__ bout_f,
    float* __restrict__ out)
{
    __shared__ __align__(16) _Float16 lsA[128 * 64];   // 16 KB
    __shared__ __align__(16) _Float16 lsB[128 * 64];   // 16 KB

    const int tid = threadIdx.x;
    const int lane = tid & 63;
    const int wid  = tid >> 6;
    const int srow = lane >> 3;                    // staging row-in-group (=row&7)
    const int skc  = (((lane & 7) ^ srow)) << 3;   // XOR-swizzled k-chunk offset
    const int wm    = (wid >> 1) * 64;             // wave m-offset
    const int wncol = wid & 1;                     // wave n-column (0/1)
    const int quad  = lane >> 4;
    const int l15   = lane & 15;
    const int bsw   = (l15 & 7);                   // fragment row&7 (bank swizzle)

    const bool is_gemm = (int)blockIdx.x < n_gemm;
    if (!is_gemm && out_t < 0) return;
    int m0, c0 = 0;
    const _Float16 *ag[4], *bg[4];

    if (is_gemm) {
        // XCD swizzle (bid%8 ~ XCD): each XCD gets 16 m-tiles x 4 n-tiles
        // => per-XCD working set: A 2 MB + B 0.5 MB < 4 MB L2
        int x = (int)blockIdx.x & 7, j = (int)blockIdx.x >> 3;
        int mt = (x & 1) * 16 + (j & 15);    // 0..31 batch tile
        int nt = (x >> 1) * 4 + (j >> 4);    // 0..15 hcol tile
        m0 = mt * 128;
        c0 = nt * 32;
        #pragma unroll
        for (int i = 0; i < 4; i++) {
            int lr = wid * 32 + i * 8 + srow;          // local row 0..127
            ag[i] = h_r + (size_t)(m0 + lr) * HD + skc;
            // local col lr -> (wavecol=lr>>6, gate=(lr>>4)&3, tcol=lr&15)
            int wr = ((lr >> 4) & 3) * HD + c0 + ((lr >> 6) << 4) + (lr & 15);
            bg[i] = W + (size_t)wr * HD + skc;
        }
    } else {
        m0 = ((int)blockIdx.x - n_gemm) * 128;
        #pragma unroll
        for (int i = 0; i < 4; i++) {
            int lr = wid * 32 + i * 8 + srow;
            ag[i] = h_r + (size_t)(m0 + lr) * HD + skc;
            bg[i] = Wout + (size_t)lr * HD + skc;      // Wout row = v
        }
    }

    fx4 acc[4][4];
    #pragma unroll
    for (int i = 0; i < 4; i++)
        #pragma unroll
        for (int j = 0; j < 4; j++)
            acc[i][j] = fx4{0.f, 0.f, 0.f, 0.f};

    for (int k0 = 0; k0 < HD; k0 += 64) {
        __syncthreads();   // protect LDS while still being read
        #pragma unroll
        for (int i = 0; i < 4; i++) {
            int lb = (wid * 32 + i * 8) * 64;          // wave-uniform LDS base
            gl2lds16(ag[i] + k0, &lsA[lb]);
            gl2lds16(bg[i] + k0, &lsB[lb]);
        }
        __syncthreads();   // drains vmcnt before barrier
        #pragma unroll
        for (int kk = 0; kk < 64; kk += 32) {
            const int kc = (kk >> 3) + quad;           // global k-chunk 0..7
            const int sw = ((kc ^ bsw) << 3);          // swizzled column (halfs)
            half8 ah[4], bh[4];
            #pragma unroll
            for (int mt = 0; mt < 4; mt++)
                ah[mt] = *(const half8*)&lsA[(wm + mt * 16 + l15) * 64 + sw];
            #pragma unroll
            for (int nt = 0; nt < 4; nt++)
                bh[nt] = *(const half8*)&lsB[(wncol * 64 + nt * 16 + l15) * 64 + sw];
            #pragma unroll
            for (int mt = 0; mt < 4; mt++)
                #pragma unroll
                for (int nt = 0; nt < 4; nt++)
                    acc[mt][nt] = __builtin_amdgcn_mfma_f32_16x16x32_f16(ah[mt], bh[nt], acc[mt][nt], 0, 0, 0);
        }
    }

    if (is_gemm) {
        // acc[mt][gate][r]: all 4 gates for (row, hcol) live in this lane
        const int hcol = c0 + wncol * 16 + l15;
        #pragma unroll
        for (int mt = 0; mt < 4; mt++) {
            #pragma unroll
            for (int r = 0; r < 4; r++) {
                int row = m0 + wm + mt * 16 + quad * 4 + r;   // batch index
                int tok = is_enc ? seq[row * SSRC + t]
                                 : (t == 0 ? 1 : seq[row * STGT + t - 1]);  // SOS=1
                const float* xp = proj + (size_t)tok * G4 + hcol;
                float gi = acc[mt][0][r] + xp[0];
                float gf = acc[mt][1][r] + xp[HD];
                float gg = acc[mt][2][r] + xp[2 * HD];
                float go = acc[mt][3][r] + xp[3 * HD];
                float ii = sigf(gi), ff = sigf(gf), oo = sigf(go);
                float g2 = tanhfast(gg);
                size_t off = (size_t)row * HD + hcol;
                float cold = c_state[off];
                float c2 = ff * cold + ii * g2;
                float h2 = oo * tanhfast(c2);
                if (is_enc && t >= lens[row]) {   // pack_padded semantics
                    c2 = cold;
                    h2 = (float)h_r[off];          // exact fp16 carry
                }
                c_state[off] = c2;
                h_w[off] = (_Float16)h2;
            }
        }
    } else {
        // logits[:, out_t, :] = h_prev @ Wout^T + bout  (fp32 output)
        #pragma unroll
        for (int mt = 0; mt < 4; mt++) {
            #pragma unroll
            for (int nt = 0; nt < 4; nt++) {
                int v = wncol * 64 + nt * 16 + l15;
                float bo = bout_f[v];
                #pragma unroll
                for (int r = 0; r < 4; r++) {
                    int row = m0 + wm + mt * 16 + quad * 4 + r;
                    out[((size_t)row * STGT + out_t) * NVTGT + v] = acc[mt][nt][r] + bo;
                }
            }
        }
    }
}

extern "C" void kernel_launch(void* const* d_in, const int* in_sizes, int n_in,
                              void* d_out, int out_size, void* d_ws, size_t ws_size,
                              hipStream_t stream) {
    (void)in_sizes; (void)n_in; (void)out_size; (void)ws_size;
    const int* src_seq = (const int*)d_in[0];
    const int* src_len = (const int*)d_in[1];
    const int* tgt_seq = (const int*)d_in[2];
    const float* emb_src = (const float*)d_in[3];
    const float* eWih = (const float*)d_in[4];
    const float* eWhh = (const float*)d_in[5];
    const float* ebih = (const float*)d_in[6];
    const float* ebhh = (const float*)d_in[7];
    const float* emb_tgt = (const float*)d_in[8];
    const float* dWih = (const float*)d_in[9];
    const float* dWhh = (const float*)d_in[10];
    const float* dbih = (const float*)d_in[11];
    const float* dbhh = (const float*)d_in[12];
    const float* Wout = (const float*)d_in[13];
    const float* bout = (const float*)d_in[14];
    float* out = (float*)d_out;   // reference output dtype is float32

    char* ws = (char*)d_ws;
    size_t off = 0;
    auto carve = [&](size_t bytes) { void* p = ws + off; off += (bytes + 255) & ~(size_t)255; return p; };
    float* proj_src = (float*)carve((size_t)NVSRC * G4 * 4);
    float* proj_tgt = (float*)carve((size_t)NVTGT * G4 * 4);
    float* bout_f   = (float*)carve(NVTGT * 4);
    float* c_state  = (float*)carve((size_t)NB * HD * 4);
    _Float16* h[2];
    for (int i = 0; i < 2; i++) h[i] = (_Float16*)carve((size_t)NB * HD * 2);
    _Float16* eW_h = (_Float16*)carve((size_t)G4 * HD * 2);
    _Float16* dW_h = (_Float16*)carve((size_t)G4 * HD * 2);
    _Float16* Wo_h = (_Float16*)carve((size_t)NVTGT * HD * 2);

    hipMemsetAsync(c_state, 0, (size_t)NB * HD * 4, stream);
    hipMemsetAsync(h[0], 0, (size_t)NB * HD * 2, stream);

    convert_half<<<dim3(G4 * HD / 256), dim3(256), 0, stream>>>(eWhh, G4 * HD, eW_h);
    convert_half<<<dim3(G4 * HD / 256), dim3(256), 0, stream>>>(dWhh, G4 * HD, dW_h);
    convert_half<<<dim3(NVTGT * HD / 256), dim3(256), 0, stream>>>(Wout, NVTGT * HD, Wo_h);
    prep_bout<<<dim3(1), dim3(128), 0, stream>>>(bout, bout_f);
    build_tables<<<dim3(NVSRC), dim3(256), 0, stream>>>(emb_src, eWih, ebih, ebhh, proj_src);
    build_tables<<<dim3(NVTGT), dim3(256), 0, stream>>>(emb_tgt, dWih, dbih, dbhh, proj_tgt);

    // encoder: steps s=0..31, masked update
    for (int s = 0; s < 32; s++) {
        lstm_step<<<dim3(512), dim3(256), 0, stream>>>(
            h[s & 1], h[(s + 1) & 1], c_state,
            proj_src, src_seq, src_len, eW_h, s, 1, 512, -1,
            Wo_h, bout_f, out);
    }
    // decoder: steps tt=0..31; 32 extra blocks project h_{tt-1} -> out[:,tt-1,:]
    for (int tt = 0; tt < 32; tt++) {
        int s = 32 + tt;
        lstm_step<<<dim3(544), dim3(256), 0, stream>>>(
            h[s & 1], h[(s + 1) & 1], c_state,
            proj_tgt, tgt_seq, nullptr, dW_h, tt, 0, 512, tt - 1,
            Wo_h, bout_f, out);
    }
    // tail: outproj of h after decoder step 31 (parity 0)
    lstm_step<<<dim3(32), dim3(256), 0, stream>>>(
        h[0], h[1], c_state,
        proj_tgt, tgt_seq, nullptr, dW_h, 0, 0, 0, 31,
        Wo_h, bout_f, out);
}